// Round 1
// baseline (326.576 us; speedup 1.0000x reference)
//
#include <hip/hip_runtime.h>

// Recall over a [B=32, F=512, T=2048] grid:
//   p_adj[b,f,t] = predicted[b, f==0?1:f, t==0?1:t]
//   out = sum(p_adj * (gt!=0)) / sum(gt!=0), or 0 if no peaks.
// Memory-bound: 256 MiB of reads, ~43 us roofline at 6.3 TB/s.

constexpr int B_ = 32;
constexpr int F_ = 512;
constexpr int T_ = 2048;
constexpr long long NTOT = (long long)B_ * F_ * T_;   // 33,554,432 = 2^25

__global__ __launch_bounds__(256) void recall_reduce(
    const float* __restrict__ pred,
    const int* __restrict__ gt,
    float* __restrict__ sum_out,
    unsigned int* __restrict__ cnt_out)
{
    const long long n4 = NTOT >> 2;                    // 8,388,608 quads
    long long tid    = (long long)blockIdx.x * blockDim.x + threadIdx.x;
    long long stride = (long long)gridDim.x * blockDim.x;

    const int4*   gt4 = (const int4*)gt;
    const float4* p4  = (const float4*)pred;

    float lsum = 0.f;
    int   lcnt = 0;

    for (long long i = tid; i < n4; i += stride) {
        int4   g = gt4[i];
        float4 p = p4[i];
        long long e = i << 2;                          // element index of lane .x
        unsigned t = (unsigned)(e & (T_ - 1));         // T = 2^11
        unsigned f = (unsigned)((e >> 11) & (F_ - 1)); // F = 2^9

        if (f != 0u && t != 0u) {
            // Interior fast path: adjusted index == own index.
            if (g.x) { lsum += p.x; ++lcnt; }
            if (g.y) { lsum += p.y; ++lcnt; }
            if (g.z) { lsum += p.z; ++lcnt; }
            if (g.w) { lsum += p.w; ++lcnt; }
        } else {
            // Edge slow path (~0.4% of quads): scalar gather at remapped index.
            long long base = (e >> 20) << 20;          // b * F*T (F*T = 2^20)
            unsigned fp = (f == 0u) ? 1u : f;
            int gv[4] = { g.x, g.y, g.z, g.w };
            #pragma unroll
            for (int j = 0; j < 4; ++j) {
                if (gv[j]) {
                    unsigned tj = t + (unsigned)j;
                    unsigned tp = (tj == 0u) ? 1u : tj;
                    lsum += pred[base + (long long)fp * T_ + tp];
                    ++lcnt;
                }
            }
        }
    }

    // Wave-64 shuffle reduction.
    #pragma unroll
    for (int off = 32; off > 0; off >>= 1) {
        lsum += __shfl_down(lsum, off, 64);
        lcnt += __shfl_down(lcnt, off, 64);
    }

    __shared__ float ssum[4];
    __shared__ int   scnt[4];
    int lane = threadIdx.x & 63;
    int wave = threadIdx.x >> 6;
    if (lane == 0) { ssum[wave] = lsum; scnt[wave] = lcnt; }
    __syncthreads();

    if (threadIdx.x == 0) {
        float bs = ssum[0] + ssum[1] + ssum[2] + ssum[3];
        int   bc = scnt[0] + scnt[1] + scnt[2] + scnt[3];
        atomicAdd(sum_out, bs);
        atomicAdd(cnt_out, (unsigned int)bc);
    }
}

__global__ void recall_finalize(const float* __restrict__ sum_in,
                                const unsigned int* __restrict__ cnt_in,
                                float* __restrict__ out)
{
    unsigned int c = *cnt_in;
    out[0] = (c > 0u) ? (*sum_in / (float)c) : 0.0f;
}

extern "C" void kernel_launch(void* const* d_in, const int* in_sizes, int n_in,
                              void* d_out, int out_size, void* d_ws, size_t ws_size,
                              hipStream_t stream)
{
    const float* pred = (const float*)d_in[0];
    const int*   gt   = (const int*)d_in[1];
    float*       out  = (float*)d_out;

    float*        sum_ws = (float*)d_ws;
    unsigned int* cnt_ws = (unsigned int*)((char*)d_ws + sizeof(float));

    // d_ws is poisoned to 0xAA before every launch — zero the accumulators.
    hipMemsetAsync(d_ws, 0, 2 * sizeof(float), stream);

    const int threads = 256;
    const int blocks  = 4096;   // 16 blocks/CU, grid-stride: 8 quads/thread
    recall_reduce<<<blocks, threads, 0, stream>>>(pred, gt, sum_ws, cnt_ws);
    recall_finalize<<<1, 1, 0, stream>>>(sum_ws, cnt_ws, out);
}

// Round 2
// 290.296 us; speedup vs baseline: 1.1250x; 1.1250x over previous
//
#include <hip/hip_runtime.h>

// Recall over [B=32, F=512, T=2048]:
//   p_adj[b,f,t] = predicted[b, f==0?1:f, t==0?1:t]
//   out = sum(p_adj * (gt!=0)) / count(gt!=0), or 0 if count==0.
//
// Strategy: branchless masked sum over RAW indices (max memory-level
// parallelism, no divergent control flow in the hot loop), plus a tiny
// edge-correction kernel for the f==0 row / t==0 column remap
// (correction = p[adj] - p[raw] at gt-nonzero edge positions; count is
// unchanged by the remap). Per-block partials in d_ws; no memset, no atomics.

constexpr int B_ = 32;
constexpr int F_ = 512;
constexpr int T_ = 2048;
constexpr long long NTOT = (long long)B_ * F_ * T_;   // 2^25
constexpr int NQ      = (int)(NTOT >> 2);             // 8,388,608 quads
constexpr int BLK     = 256;
constexpr int NBLK    = 4096;
constexpr int PER_THR = 8;                            // NQ / (BLK*NBLK)
static_assert((long long)BLK * NBLK * PER_THR == NQ, "exact cover");

constexpr int EDGE_ITEMS = B_ * T_ + B_ * F_;         // 81,920
constexpr int EDGE_BLKS  = EDGE_ITEMS / BLK;          // 320

// ---------------- block reduction helper ----------------
__device__ __forceinline__ void block_reduce(float& s, int& c) {
    #pragma unroll
    for (int off = 32; off > 0; off >>= 1) {
        s += __shfl_down(s, off, 64);
        c += __shfl_down(c, off, 64);
    }
    __shared__ float ss[4];
    __shared__ int   sc[4];
    int lane = threadIdx.x & 63, wave = threadIdx.x >> 6;
    if (lane == 0) { ss[wave] = s; sc[wave] = c; }
    __syncthreads();
    if (threadIdx.x == 0) {
        s = ss[0] + ss[1] + ss[2] + ss[3];
        c = sc[0] + sc[1] + sc[2] + sc[3];
    }
}

// ---------------- main branchless masked sum ----------------
__global__ __launch_bounds__(256) void recall_main(
    const float4* __restrict__ p4,
    const int4* __restrict__ g4,
    float* __restrict__ bsum,
    unsigned int* __restrict__ bcnt)
{
    const unsigned tid    = blockIdx.x * BLK + threadIdx.x;
    const unsigned STRIDE = (unsigned)BLK * NBLK;      // 1,048,576

    int4   g[PER_THR];
    float4 p[PER_THR];
    #pragma unroll
    for (int k = 0; k < PER_THR; ++k) {
        size_t q = (size_t)tid + (size_t)k * STRIDE;
        g[k] = g4[q];
        p[k] = p4[q];
    }

    float lsum = 0.f;
    int   lcnt = 0;
    #pragma unroll
    for (int k = 0; k < PER_THR; ++k) {
        lcnt += (g[k].x != 0) + (g[k].y != 0) + (g[k].z != 0) + (g[k].w != 0);
        lsum += (g[k].x ? p[k].x : 0.f);
        lsum += (g[k].y ? p[k].y : 0.f);
        lsum += (g[k].z ? p[k].z : 0.f);
        lsum += (g[k].w ? p[k].w : 0.f);
    }

    block_reduce(lsum, lcnt);
    if (threadIdx.x == 0) {
        bsum[blockIdx.x] = lsum;
        bcnt[blockIdx.x] = (unsigned int)lcnt;
    }
}

// ---------------- edge-remap correction ----------------
// Items [0, B*T):          f==0 row  (all t; remap f->1, t->max(t,1))
// Items [B*T, B*T + B*F):  t==0 col, f>=1 only (remap t->1); f==0 cell skipped
__global__ __launch_bounds__(256) void recall_edge(
    const float* __restrict__ pred,
    const int* __restrict__ gt,
    float* __restrict__ csum)
{
    unsigned idx = blockIdx.x * BLK + threadIdx.x;
    float corr = 0.f;
    if (idx < (unsigned)(B_ * T_)) {
        unsigned b = idx >> 11, t = idx & (T_ - 1);
        unsigned raw = (b << 20) | t;
        unsigned tp  = (t == 0u) ? 1u : t;
        unsigned adj = (b << 20) | (1u << 11) | tp;
        if (gt[raw]) corr = pred[adj] - pred[raw];
    } else {
        unsigned i2 = idx - (unsigned)(B_ * T_);
        unsigned b = i2 >> 9, f = i2 & (F_ - 1);
        if (f != 0u) {
            unsigned raw = (b << 20) | (f << 11);
            if (gt[raw]) corr = pred[raw + 1] - pred[raw];
        }
    }
    int dummy = 0;
    block_reduce(corr, dummy);
    if (threadIdx.x == 0) csum[blockIdx.x] = corr;
}

// ---------------- finalize ----------------
__global__ __launch_bounds__(256) void recall_fin(
    const float* __restrict__ bsum,
    const unsigned int* __restrict__ bcnt,
    const float* __restrict__ csum,
    float* __restrict__ out)
{
    float s = 0.f;
    int   c = 0;
    for (int j = threadIdx.x; j < NBLK; j += BLK) {
        s += bsum[j];
        c += (int)bcnt[j];
    }
    for (int j = threadIdx.x; j < EDGE_BLKS; j += BLK) s += csum[j];

    block_reduce(s, c);
    if (threadIdx.x == 0)
        out[0] = (c > 0) ? (s / (float)c) : 0.0f;
}

extern "C" void kernel_launch(void* const* d_in, const int* in_sizes, int n_in,
                              void* d_out, int out_size, void* d_ws, size_t ws_size,
                              hipStream_t stream)
{
    const float* pred = (const float*)d_in[0];
    const int*   gt   = (const int*)d_in[1];
    float*       out  = (float*)d_out;

    float*        bsum = (float*)d_ws;
    unsigned int* bcnt = (unsigned int*)((char*)d_ws + NBLK * sizeof(float));
    float*        csum = (float*)((char*)d_ws + 2 * NBLK * sizeof(float));

    recall_main<<<NBLK, BLK, 0, stream>>>((const float4*)pred, (const int4*)gt,
                                          bsum, bcnt);
    recall_edge<<<EDGE_BLKS, BLK, 0, stream>>>(pred, gt, csum);
    recall_fin<<<1, BLK, 0, stream>>>(bsum, bcnt, csum, out);
}